// Round 8
// baseline (622.996 us; speedup 1.0000x reference)
//
#include <hip/hip_runtime.h>

// GenLSTM: B=8192, T=256 (255 steps), noise=8, seq_dim=4, HID=64, gates=256.
// R13: structural anti-phase. R12 post-mortem: non-draining barriers REGRESSED
// (314->330; vmcnt drain was not an exposed stall) -> __syncthreads restored.
// R11 proved the two co-resident chains convoy (s_sleep skew +10%) but nothing
// LOCKS the phase. R13 puts both chains in ONE block (256 blocks x 512 thr,
// M=32 as two 16-row groups A=waves0-3, B=waves4-7) staggered ONE SEGMENT apart
// so the shared barriers themselves enforce anti-phase every step:
//   slot1 {A:C(t), B:Y1(t)} | slot2 {A:Y1, B:Y2} | slot3 {A:Y2, B:C(t+1)}
// where C = tail-MFMAs+cell (VALU-heavy), Y1 = y1+gate-h (MFMA), Y2 = y2.
// Each group's producer->consumer (h, y1, y2 buffers) still crosses exactly one
// barrier. B enters one slot early via pre-loop segC(0) + stagger barrier.
// Wave i -> SIMD i&3: each SIMD hosts one A-wave + one B-wave, so each SIMD
// always has one VALU-phase and one MFMA-phase wave -- the R11 skew made
// structural. Per-wave state/registers unchanged vs R11 (~124 VGPR); LDS 13.8KB;
// 8 waves/CU as before. s_sleep removed (1 block/CU; nothing to skew against).
// Kept: W3W fold, register noise B-frag (prefetch 1 step ahead), bias b' in wgn
// row k=8 (B=1 via quad1 nf0.x), exp2-prescaled gates, 7-trans cell, setprio(1)
// over MFMA segments.

typedef _Float16 h8 __attribute__((ext_vector_type(8)));
typedef __fp16 p2h __attribute__((ext_vector_type(2)));
typedef float f4 __attribute__((ext_vector_type(4)));

#define MFMA(a, b, c) __builtin_amdgcn_mfma_f32_16x16x32_f16(a, b, c, 0, 0, 0)
#define EXP2(x) __builtin_amdgcn_exp2f(x)

constexpr int SEQ = 256, STEPS = 255, ND = 8, SD = 4, HID = 64, G4 = 256;
constexpr int HST = 72;  // h/y row stride (f16): 16B-aligned rows
constexpr float LOG2E = 1.44269504f;

__device__ __forceinline__ void store4h(_Float16* p, f4 v) {
    p2h lo = __builtin_amdgcn_cvt_pkrtz(v[0], v[1]);
    p2h hi = __builtin_amdgcn_cvt_pkrtz(v[2], v[3]);
    float2 st;
    st.x = __builtin_bit_cast(float, lo);
    st.y = __builtin_bit_cast(float, hi);
    *(float2*)p = st;
}

__global__ __launch_bounds__(512, 2) void genlstm_kernel(
    const float* __restrict__ noise, const float* __restrict__ Wx,
    const float* __restrict__ Wh, const float* __restrict__ b,
    const float* __restrict__ W1, const float* __restrict__ b1,
    const float* __restrict__ W2, const float* __restrict__ b2,
    const float* __restrict__ W3, const float* __restrict__ b3,
    float* __restrict__ out)
{
    __shared__ alignas(16) _Float16 Hb[2][16 * HST];   // [grp][row][HST]
    __shared__ alignas(16) _Float16 Y1b[2][16 * HST];
    __shared__ alignas(16) _Float16 Y2b[2][16 * HST];

    const int tid = threadIdx.x, wid = tid >> 6, lane = tid & 63;
    const int grp = wid >> 2;            // 0 = group A, 1 = group B (one slot ahead)
    const int wv = wid & 3;              // in-group wave: gate/col split
    const int col = lane & 15, quad = lane >> 4, q8 = quad * 8;
    const int brow = blockIdx.x * 32;
    const int row0 = brow + grp * 16;
    const int n0 = wv * 16 + col;        // gate/hid col for weight frags
    const int wq = wv * 16 + quad * 4;   // C^T write col base

    const float gsc[4] = {LOG2E, LOG2E, 2.f * LOG2E, LOG2E};  // i,f,g,o

    // ---- gate weight frags: Wh slices (k=0..63), exp2-prescaled ----
    h8 wg[4][2];
    #pragma unroll
    for (int g = 0; g < 4; ++g)
        #pragma unroll
        for (int s = 0; s < 2; ++s)
            #pragma unroll
            for (int j = 0; j < 8; ++j)
                wg[g][s][j] = (_Float16)(Wh[(32 * s + q8 + j) * G4 + 64 * g + n0] * gsc[g]);

    // ---- noise+bias slice: k=0..7 -> Wxn rows (quad0), k=8 -> b' row ----
    // b' = b + b3 @ Wx_x (the x-fold bias), prescaled.
    h8 wgn[4];
    #pragma unroll
    for (int g = 0; g < 4; ++g)
        #pragma unroll
        for (int j = 0; j < 8; ++j) {
            const int k = q8 + j;
            const int n = 64 * g + n0;
            float v = 0.0f;
            if (k < 8) v = Wx[(4 + k) * G4 + n];
            else if (k == 8) {
                float bx = b3[0] * Wx[0 * G4 + n] + b3[1] * Wx[1 * G4 + n] +
                           b3[2] * Wx[2 * G4 + n] + b3[3] * Wx[3 * G4 + n];
                v = b[n] + bx;
            }
            wgn[g][j] = (_Float16)(v * gsc[g]);
        }

    // ---- W3W = W3 @ Wx[0:4,:] fold (prescaled): z += y2 @ W3W ----
    h8 wgy[4][2];
    #pragma unroll
    for (int s = 0; s < 2; ++s)
        #pragma unroll
        for (int j = 0; j < 8; ++j) {
            const int k = 32 * s + q8 + j;
            const float w30 = W3[k * SD + 0], w31 = W3[k * SD + 1];
            const float w32 = W3[k * SD + 2], w33 = W3[k * SD + 3];
            #pragma unroll
            for (int g = 0; g < 4; ++g) {
                const int n = 64 * g + n0;
                float acc = w30 * Wx[0 * G4 + n] + w31 * Wx[1 * G4 + n] +
                            w32 * Wx[2 * G4 + n] + w33 * Wx[3 * G4 + n];
                wgy[g][s][j] = (_Float16)(acc * gsc[g]);
            }
        }
    // ---- MLP weight frags (wave-split, 16 cols each) ----
    h8 w1f[2], w2f[2], w3f[2];
    #pragma unroll
    for (int s = 0; s < 2; ++s)
        #pragma unroll
        for (int j = 0; j < 8; ++j) {
            const int k = 32 * s + q8 + j;
            w1f[s][j] = (_Float16)W1[k * HID + n0];
            w2f[s][j] = (_Float16)W2[k * HID + n0];
            w3f[s][j] = (_Float16)(col < 4 ? W3[k * SD + col] : 0.0f);
        }
    f4 b1v, b2v, b3v;
    #pragma unroll
    for (int r = 0; r < 4; ++r) {
        b1v[r] = b1[wq + r];
        b2v[r] = b2[wq + r];
        b3v[r] = (quad == 0) ? b3[r] : 0.0f;
    }

    if (tid < 32) {  // out[:,0,:] = 0 for this block's 32 rows
        float4 z; z.x = z.y = z.z = z.w = 0.0f;
        *(float4*)(out + (size_t)(brow + tid) * SEQ * SD) = z;
    }

    _Float16* Hrow = &Hb[grp][col * HST];
    _Float16* Y1row = &Y1b[grp][col * HST];
    _Float16* Y2row = &Y2b[grp][col * HST];
    float* outp = out + ((size_t)(row0 + col) * SEQ + 1) * SD;

    // noise: quad0 lanes own all 8 dims of batch row (row0+col)
    const float* npt = noise + (size_t)(row0 + col) * SEQ * ND;

    const f4 fz = {0.f, 0.f, 0.f, 0.f};
    f4 cst = fz, run = fz;
    f4 zi, zf, zg, zo;

    // nf persists; only quad0 reloads it. After the prologue, quad1's nf0.x is
    // the constant 1.0 feeding the b' bias row (k=8).
    float4 nf0, nf1;
    nf0.x = nf0.y = nf0.z = nf0.w = 0.f;
    nf1 = nf0;

    // ---- prologue (both groups): z(0) = noise(0) @ Wxn + b ----
    {
        if (quad == 0) { nf0 = *(const float4*)npt; nf1 = *(const float4*)(npt + 4); }
        npt += ND;
        union { h8 v; p2h p[4]; } nb;
        nb.p[0] = __builtin_amdgcn_cvt_pkrtz(nf0.x, nf0.y);
        nb.p[1] = __builtin_amdgcn_cvt_pkrtz(nf0.z, nf0.w);
        nb.p[2] = __builtin_amdgcn_cvt_pkrtz(nf1.x, nf1.y);
        nb.p[3] = __builtin_amdgcn_cvt_pkrtz(nf1.z, nf1.w);
        #pragma unroll
        for (int g = 0; g < 4; ++g) {
            f4 tb;  // transient prologue bias b*gsc
            #pragma unroll
            for (int r = 0; r < 4; ++r) tb[r] = b[64 * g + wq + r] * gsc[g];
            f4 z0 = MFMA(wgn[g], nb.v, tb);
            if (g == 0) zi = z0; else if (g == 1) zf = z0;
            else if (g == 2) zg = z0; else zo = z0;
        }
        if (quad == 1) nf0.x = 1.0f;  // enable b' bias row from step 1 on
    }

    // ---- segments ----
    // C(t): [t>0] read y2(t-1), complete z(t) (noise+b', W3W), emit x(t);
    //       [t<STEPS] cell(t) -> h(t+1); prefetch noise(t+1).
    auto segC = [&](int t) {
        if (t > 0) {
            h8 q0 = *(const h8*)(Y2row + q8);
            h8 q1 = *(const h8*)(Y2row + 32 + q8);
            union { h8 v; p2h p[4]; } nb;  // noise(t), loaded during segC(t-1)
            nb.p[0] = __builtin_amdgcn_cvt_pkrtz(nf0.x, nf0.y);
            nb.p[1] = __builtin_amdgcn_cvt_pkrtz(nf0.z, nf0.w);
            nb.p[2] = __builtin_amdgcn_cvt_pkrtz(nf1.x, nf1.y);
            nb.p[3] = __builtin_amdgcn_cvt_pkrtz(nf1.z, nf1.w);
            if (t < STEPS && quad == 0) {  // prefetch noise(t+1)
                nf0 = *(const float4*)npt; nf1 = *(const float4*)(npt + 4);
            }
            npt += ND;
            zi = MFMA(wgn[0], nb.v, zi);
            zf = MFMA(wgn[1], nb.v, zf);
            zg = MFMA(wgn[2], nb.v, zg);
            zo = MFMA(wgn[3], nb.v, zo);
            zi = MFMA(wgy[0][0], q0, zi); zi = MFMA(wgy[0][1], q1, zi);
            zf = MFMA(wgy[1][0], q0, zf); zf = MFMA(wgy[1][1], q1, zf);
            zg = MFMA(wgy[2][0], q0, zg); zg = MFMA(wgy[2][1], q1, zg);
            zo = MFMA(wgy[3][0], q0, zo); zo = MFMA(wgy[3][1], q1, zo);
            if (wv == 0) {  // x(t) = y2(t-1) @ W3 + b3, output only
                f4 x = MFMA(w3f[0], q0, b3v);
                x = MFMA(w3f[1], q1, x);
                if (quad == 0) {
                    run += x;
                    *(f4*)outp = run;  // cumsum output, dwordx4
                }
            }
            outp += SD;
        } else {  // t == 0: z(0) came from the prologue; just prefetch noise(1)
            if (quad == 0) { nf0 = *(const float4*)npt; nf1 = *(const float4*)(npt + 4); }
            npt += ND;
        }
        if (t < STEPS) {
            // cell update; 7 trans, exp2-prescaled
            f4 hv;
            #pragma unroll
            for (int r = 0; r < 4; ++r) {
                float Ei = EXP2(-fmaxf(zi[r], -15.f * LOG2E));
                float Ef = EXP2(-fmaxf(zf[r], -15.f * LOG2E));
                float Eg = EXP2(-fmaxf(zg[r], -30.f * LOG2E));
                float Eo = EXP2(-zo[r]);
                float Di = 1.f + Ei, Df = 1.f + Ef, Dg = 1.f + Eg, Do = 1.f + Eo;
                float DiDg = Di * Dg;
                float cn = (cst[r] * DiDg + (2.f - Dg) * Df) *
                           __builtin_amdgcn_rcpf(Df * DiDg);
                cst[r] = cn;
                float Ec = EXP2(fmaxf(cn, -15.f) * (-2.f * LOG2E));
                hv[r] = (1.f - Ec) * __builtin_amdgcn_rcpf(Do * (1.f + Ec));
            }
            store4h(Hrow + wq, hv);  // h(t+1)
        }
    };
    // Y1: y1 = relu(h @ W1 + b1); pipelined gate-h MFMAs for z(t+1)
    auto segY1 = [&]() {
        __builtin_amdgcn_s_setprio(1);
        h8 h0 = *(const h8*)(Hrow + q8);
        h8 h1 = *(const h8*)(Hrow + 32 + q8);
        f4 y1 = MFMA(w1f[0], h0, b1v);
        y1 = MFMA(w1f[1], h1, y1);
        #pragma unroll
        for (int r = 0; r < 4; ++r) y1[r] = fmaxf(y1[r], 0.f);
        store4h(Y1row + wq, y1);
        zi = MFMA(wg[0][0], h0, fz); zi = MFMA(wg[0][1], h1, zi);
        zf = MFMA(wg[1][0], h0, fz); zf = MFMA(wg[1][1], h1, zf);
        zg = MFMA(wg[2][0], h0, fz); zg = MFMA(wg[2][1], h1, zg);
        zo = MFMA(wg[3][0], h0, fz); zo = MFMA(wg[3][1], h1, zo);
        __builtin_amdgcn_s_setprio(0);
    };
    // Y2: y2 = relu(y1 @ W2 + b2)
    auto segY2 = [&]() {
        __builtin_amdgcn_s_setprio(1);
        h8 p0 = *(const h8*)(Y1row + q8);
        h8 p1 = *(const h8*)(Y1row + 32 + q8);
        f4 y2 = MFMA(w2f[0], p0, b2v);
        y2 = MFMA(w2f[1], p1, y2);
        #pragma unroll
        for (int r = 0; r < 4; ++r) y2[r] = fmaxf(y2[r], 0.f);
        store4h(Y2row + wq, y2);
        __builtin_amdgcn_s_setprio(0);
    };

    // ---- stagger: B runs one slot ahead ----
    if (grp) segC(0);
    __syncthreads();

    #pragma unroll 1
    for (int t = 0; t < STEPS; ++t) {
        if (!grp) segC(t);   else segY1();
        __syncthreads();
        if (!grp) segY1();   else segY2();
        __syncthreads();
        if (!grp) segY2();   else segC(t + 1);
        __syncthreads();
    }
    if (!grp) segC(STEPS);  // A's final x(255) (R3-only: t==STEPS skips cell)
}

extern "C" void kernel_launch(void* const* d_in, const int* in_sizes, int n_in,
                              void* d_out, int out_size, void* d_ws, size_t ws_size,
                              hipStream_t stream) {
    genlstm_kernel<<<256, 512, 0, stream>>>(
        (const float*)d_in[0], (const float*)d_in[1], (const float*)d_in[2],
        (const float*)d_in[3], (const float*)d_in[4], (const float*)d_in[5],
        (const float*)d_in[6], (const float*)d_in[7], (const float*)d_in[8],
        (const float*)d_in[9], (float*)d_out);
}

// Round 9
// 608.343 us; speedup vs baseline: 1.0241x; 1.0241x over previous
//
#include <hip/hip_runtime.h>

// GenLSTM: B=8192, T=256 (255 steps), noise=8, seq_dim=4, HID=64, gates=256.
// R14: wave specialization inside the R11 skeleton. R13 post-mortem: fusing the
// two chains into one 8-wave barrier domain dropped to 1 block/CU, exposed full
// rendezvous every slot and spilled (WRITE +12MB) => 570us. Lessons held: <=128
// VGPR per role; keep TWO independent blocks/CU. R14 keeps R11's dataflow
// EXACTLY (512 blocks, 3 barriers/step, skew, same producer/consumer slots) but
// splits roles across 6 waves/block: waves 0-3 = gate (cell + gate-h + tail z;
// wg/wgn/wgy ~80 regs, no W1/W2), waves 4-5 = MLP (y1/y2/x; w1/w2 tiles ~50
// regs). Barrier counts identical in both role loops (3 x 255). Wins sought:
// 12 waves/CU (3/SIMD, +50% TLP), role-pure short instruction streams, real
// role diversity for setprio (cell-VALU waves vs MFMA waves on each SIMD).
// Kept: W3W fold, register noise B-frag (1-step prefetch), bias b' in wgn row
// k=8 (B=1 via quad1 nf0.x), exp2-prescaled gates, 7-trans cell, s_sleep skew.

typedef _Float16 h8 __attribute__((ext_vector_type(8)));
typedef __fp16 p2h __attribute__((ext_vector_type(2)));
typedef float f4 __attribute__((ext_vector_type(4)));

#define MFMA(a, b, c) __builtin_amdgcn_mfma_f32_16x16x32_f16(a, b, c, 0, 0, 0)
#define EXP2(x) __builtin_amdgcn_exp2f(x)

constexpr int SEQ = 256, STEPS = 255, ND = 8, SD = 4, HID = 64, G4 = 256;
constexpr int HST = 72;  // h/y row stride (f16): 16B-aligned rows
constexpr float LOG2E = 1.44269504f;

__device__ __forceinline__ void store4h(_Float16* p, f4 v) {
    p2h lo = __builtin_amdgcn_cvt_pkrtz(v[0], v[1]);
    p2h hi = __builtin_amdgcn_cvt_pkrtz(v[2], v[3]);
    float2 st;
    st.x = __builtin_bit_cast(float, lo);
    st.y = __builtin_bit_cast(float, hi);
    *(float2*)p = st;
}

__global__ __launch_bounds__(384, 2) void genlstm_kernel(
    const float* __restrict__ noise, const float* __restrict__ Wx,
    const float* __restrict__ Wh, const float* __restrict__ b,
    const float* __restrict__ W1, const float* __restrict__ b1,
    const float* __restrict__ W2, const float* __restrict__ b2,
    const float* __restrict__ W3, const float* __restrict__ b3,
    float* __restrict__ out)
{
    __shared__ alignas(16) _Float16 Hb[16 * HST];
    __shared__ alignas(16) _Float16 Y1b[16 * HST];
    __shared__ alignas(16) _Float16 Y2b[16 * HST];

    const int tid = threadIdx.x, wid = tid >> 6, lane = tid & 63;
    const int col = lane & 15, quad = lane >> 4, q8 = quad * 8;
    const int row0 = blockIdx.x * 16;

    if (tid < 16) {  // out[:,0,:] = 0
        float4 z; z.x = z.y = z.z = z.w = 0.0f;
        *(float4*)(out + (size_t)(row0 + tid) * SEQ * SD) = z;
    }

    // anti-convoy skew between the two co-resident blocks (pair = b, b+256)
    if (blockIdx.x & 256) __builtin_amdgcn_s_sleep(26);

    if (wid < 4) {
        // ================= GATE ROLE (waves 0-3) =================
        const int wv = wid;
        const int n0 = wv * 16 + col;       // gate col for weight frags
        const int wq = wv * 16 + quad * 4;  // C^T write col base
        const float gsc[4] = {LOG2E, LOG2E, 2.f * LOG2E, LOG2E};  // i,f,g,o

        // Wh slices (k=0..63), exp2-prescaled
        h8 wg[4][2];
        #pragma unroll
        for (int g = 0; g < 4; ++g)
            #pragma unroll
            for (int s = 0; s < 2; ++s)
                #pragma unroll
                for (int j = 0; j < 8; ++j)
                    wg[g][s][j] = (_Float16)(Wh[(32 * s + q8 + j) * G4 + 64 * g + n0] * gsc[g]);

        // noise+bias slice: k=0..7 -> Wxn rows (quad0), k=8 -> b' row
        h8 wgn[4];
        #pragma unroll
        for (int g = 0; g < 4; ++g)
            #pragma unroll
            for (int j = 0; j < 8; ++j) {
                const int k = q8 + j;
                const int n = 64 * g + n0;
                float v = 0.0f;
                if (k < 8) v = Wx[(4 + k) * G4 + n];
                else if (k == 8) {
                    float bx = b3[0] * Wx[0 * G4 + n] + b3[1] * Wx[1 * G4 + n] +
                               b3[2] * Wx[2 * G4 + n] + b3[3] * Wx[3 * G4 + n];
                    v = b[n] + bx;
                }
                wgn[g][j] = (_Float16)(v * gsc[g]);
            }

        // W3W = W3 @ Wx[0:4,:] fold (prescaled)
        h8 wgy[4][2];
        #pragma unroll
        for (int s = 0; s < 2; ++s)
            #pragma unroll
            for (int j = 0; j < 8; ++j) {
                const int k = 32 * s + q8 + j;
                const float w30 = W3[k * SD + 0], w31 = W3[k * SD + 1];
                const float w32 = W3[k * SD + 2], w33 = W3[k * SD + 3];
                #pragma unroll
                for (int g = 0; g < 4; ++g) {
                    const int n = 64 * g + n0;
                    float acc = w30 * Wx[0 * G4 + n] + w31 * Wx[1 * G4 + n] +
                                w32 * Wx[2 * G4 + n] + w33 * Wx[3 * G4 + n];
                    wgy[g][s][j] = (_Float16)(acc * gsc[g]);
                }
            }

        _Float16* Hrow = &Hb[col * HST];
        const _Float16* Y2row = &Y2b[col * HST];
        const float* npt = noise + (size_t)(row0 + col) * SEQ * ND;

        const f4 fz = {0.f, 0.f, 0.f, 0.f};
        f4 cst = fz;
        f4 zi, zf, zg, zo;
        float4 nf0, nf1;
        nf0.x = nf0.y = nf0.z = nf0.w = 0.f;
        nf1 = nf0;

        // prologue: z(0) = noise(0) @ Wxn + b  (x(0)=0 -> plain b, transient)
        {
            if (quad == 0) { nf0 = *(const float4*)npt; nf1 = *(const float4*)(npt + 4); }
            npt += ND;
            union { h8 v; p2h p[4]; } nb;
            nb.p[0] = __builtin_amdgcn_cvt_pkrtz(nf0.x, nf0.y);
            nb.p[1] = __builtin_amdgcn_cvt_pkrtz(nf0.z, nf0.w);
            nb.p[2] = __builtin_amdgcn_cvt_pkrtz(nf1.x, nf1.y);
            nb.p[3] = __builtin_amdgcn_cvt_pkrtz(nf1.z, nf1.w);
            #pragma unroll
            for (int g = 0; g < 4; ++g) {
                f4 tb;
                #pragma unroll
                for (int r = 0; r < 4; ++r) tb[r] = b[64 * g + wq + r] * gsc[g];
                f4 z0 = MFMA(wgn[g], nb.v, tb);
                if (g == 0) zi = z0; else if (g == 1) zf = z0;
                else if (g == 2) zg = z0; else zo = z0;
            }
            if (quad == 1) nf0.x = 1.0f;  // b' bias row from step 1 on
        }

        __builtin_amdgcn_s_setprio(1);  // cell/tail = block critical path
        #pragma unroll 1
        for (int t = 0; t < STEPS; ++t) {
            if (quad == 0) { nf0 = *(const float4*)npt; nf1 = *(const float4*)(npt + 4); }
            npt += ND;

            // cell update; 7 trans, exp2-prescaled
            f4 hv;
            #pragma unroll
            for (int r = 0; r < 4; ++r) {
                float Ei = EXP2(-fmaxf(zi[r], -15.f * LOG2E));
                float Ef = EXP2(-fmaxf(zf[r], -15.f * LOG2E));
                float Eg = EXP2(-fmaxf(zg[r], -30.f * LOG2E));
                float Eo = EXP2(-zo[r]);
                float Di = 1.f + Ei, Df = 1.f + Ef, Dg = 1.f + Eg, Do = 1.f + Eo;
                float DiDg = Di * Dg;
                float cn = (cst[r] * DiDg + (2.f - Dg) * Df) *
                           __builtin_amdgcn_rcpf(Df * DiDg);
                cst[r] = cn;
                float Ec = EXP2(fmaxf(cn, -15.f) * (-2.f * LOG2E));
                hv[r] = (1.f - Ec) * __builtin_amdgcn_rcpf(Do * (1.f + Ec));
            }
            store4h(Hrow + wq, hv);  // h(t+1)
            __syncthreads();  // B1
            __builtin_amdgcn_s_setprio(0);  // MLP waves own the path now

            // pipelined gate-h for z(t+1)
            zi = MFMA(wg[0][0], *(const h8*)(Hrow + q8), fz);
            zi = MFMA(wg[0][1], *(const h8*)(Hrow + 32 + q8), zi);
            {
                h8 h0 = *(const h8*)(Hrow + q8);
                h8 h1 = *(const h8*)(Hrow + 32 + q8);
                zf = MFMA(wg[1][0], h0, fz); zf = MFMA(wg[1][1], h1, zf);
                zg = MFMA(wg[2][0], h0, fz); zg = MFMA(wg[2][1], h1, zg);
                zo = MFMA(wg[3][0], h0, fz); zo = MFMA(wg[3][1], h1, zo);
            }
            __syncthreads();  // B2 (gate waves idle in Y2 slot)
            __syncthreads();  // B3
            __builtin_amdgcn_s_setprio(1);  // tail z is on the path

            h8 q0 = *(const h8*)(Y2row + q8);
            h8 q1 = *(const h8*)(Y2row + 32 + q8);
            union { h8 v; p2h p[4]; } nb;  // noise(t+1), prefetched
            nb.p[0] = __builtin_amdgcn_cvt_pkrtz(nf0.x, nf0.y);
            nb.p[1] = __builtin_amdgcn_cvt_pkrtz(nf0.z, nf0.w);
            nb.p[2] = __builtin_amdgcn_cvt_pkrtz(nf1.x, nf1.y);
            nb.p[3] = __builtin_amdgcn_cvt_pkrtz(nf1.z, nf1.w);
            zi = MFMA(wgn[0], nb.v, zi);
            zf = MFMA(wgn[1], nb.v, zf);
            zg = MFMA(wgn[2], nb.v, zg);
            zo = MFMA(wgn[3], nb.v, zo);
            zi = MFMA(wgy[0][0], q0, zi); zi = MFMA(wgy[0][1], q1, zi);
            zf = MFMA(wgy[1][0], q0, zf); zf = MFMA(wgy[1][1], q1, zf);
            zg = MFMA(wgy[2][0], q0, zg); zg = MFMA(wgy[2][1], q1, zg);
            zo = MFMA(wgy[3][0], q0, zo); zo = MFMA(wgy[3][1], q1, zo);
        }
    } else {
        // ================= MLP ROLE (waves 4-5) =================
        const int mw = wid - 4;  // 0: y-cols 0..31 (+x/out), 1: y-cols 32..63
        h8 w1m[2][2], w2m[2][2], w3f[2];
        #pragma unroll
        for (int tn = 0; tn < 2; ++tn)
            #pragma unroll
            for (int s = 0; s < 2; ++s)
                #pragma unroll
                for (int j = 0; j < 8; ++j) {
                    const int k = 32 * s + q8 + j;
                    const int n = 32 * mw + 16 * tn + col;
                    w1m[tn][s][j] = (_Float16)W1[k * HID + n];
                    w2m[tn][s][j] = (_Float16)W2[k * HID + n];
                }
        #pragma unroll
        for (int s = 0; s < 2; ++s)
            #pragma unroll
            for (int j = 0; j < 8; ++j) {
                const int k = 32 * s + q8 + j;
                w3f[s][j] = (_Float16)((mw == 0 && col < 4) ? W3[k * SD + col] : 0.0f);
            }
        f4 b1m[2], b2m[2], b3v;
        #pragma unroll
        for (int r = 0; r < 4; ++r) {
            #pragma unroll
            for (int tn = 0; tn < 2; ++tn) {
                b1m[tn][r] = b1[32 * mw + 16 * tn + quad * 4 + r];
                b2m[tn][r] = b2[32 * mw + 16 * tn + quad * 4 + r];
            }
            b3v[r] = (quad == 0) ? b3[r] : 0.0f;
        }

        const _Float16* Hrow = &Hb[col * HST];
        _Float16* Y1row = &Y1b[col * HST];
        _Float16* Y2row = &Y2b[col * HST];
        float* outp = out + ((size_t)(row0 + col) * SEQ + 1) * SD;
        const f4 fz = {0.f, 0.f, 0.f, 0.f};
        f4 run = fz;

        __builtin_amdgcn_s_setprio(1);  // y1/y2 are the Y-slot critical path
        #pragma unroll 1
        for (int t = 0; t < STEPS; ++t) {
            __syncthreads();  // B1
            h8 h0 = *(const h8*)(Hrow + q8);
            h8 h1 = *(const h8*)(Hrow + 32 + q8);
            #pragma unroll
            for (int tn = 0; tn < 2; ++tn) {
                f4 y1 = MFMA(w1m[tn][0], h0, b1m[tn]);
                y1 = MFMA(w1m[tn][1], h1, y1);
                #pragma unroll
                for (int r = 0; r < 4; ++r) y1[r] = fmaxf(y1[r], 0.f);
                store4h(Y1row + 32 * mw + 16 * tn + 4 * quad, y1);
            }
            __syncthreads();  // B2
            h8 p0 = *(const h8*)(Y1row + q8);
            h8 p1 = *(const h8*)(Y1row + 32 + q8);
            #pragma unroll
            for (int tn = 0; tn < 2; ++tn) {
                f4 y2 = MFMA(w2m[tn][0], p0, b2m[tn]);
                y2 = MFMA(w2m[tn][1], p1, y2);
                #pragma unroll
                for (int r = 0; r < 4; ++r) y2[r] = fmaxf(y2[r], 0.f);
                store4h(Y2row + 32 * mw + 16 * tn + 4 * quad, y2);
            }
            __syncthreads();  // B3
            if (mw == 0) {  // x(t+1) = y2 @ W3 + b3 -> cumsum output
                h8 q0 = *(const h8*)(Y2row + q8);
                h8 q1 = *(const h8*)(Y2row + 32 + q8);
                f4 x = MFMA(w3f[0], q0, b3v);
                x = MFMA(w3f[1], q1, x);
                if (quad == 0) {
                    run += x;
                    *(f4*)outp = run;  // dwordx4
                }
            }
            outp += SD;
        }
    }
}

extern "C" void kernel_launch(void* const* d_in, const int* in_sizes, int n_in,
                              void* d_out, int out_size, void* d_ws, size_t ws_size,
                              hipStream_t stream) {
    genlstm_kernel<<<512, 384, 0, stream>>>(
        (const float*)d_in[0], (const float*)d_in[1], (const float*)d_in[2],
        (const float*)d_in[3], (const float*)d_in[4], (const float*)d_in[5],
        (const float*)d_in[6], (const float*)d_in[7], (const float*)d_in[8],
        (const float*)d_in[9], (float*)d_out);
}